// Round 2
// baseline (16427.307 us; speedup 1.0000x reference)
//
#include <hip/hip_runtime.h>
#include <math.h>

#define NTOK 58
#define EPS 1e-5f
#define SB 32

struct Params {
  const float *x;
  const float *mg_w,*mg_b,*mg_g,*mg_be;
  const float *dm_w,*dm_b,*dm_g,*dm_be;
  const float *al_w,*al_b,*al_g,*al_be;
  const float *mv_w,*mv_b,*mv_g,*mv_be;
  const float *sa_in_w,*sa_in_b,*sa_out_w,*sa_out_b,*san_g,*san_b;
  const float *ff_w1,*ff_b1,*ff_w2,*ff_b2,*saf_g,*saf_b;
  const float *ca_in_w,*ca_in_b,*ca_out_w,*ca_out_b,*can_g,*can_b;
  const float *pool_w,*pool_b,*pool_g,*pool_be;
  const float *z_w1,*z_b1,*z_w2,*z_b2,*z_g,*z_be;
  const float *y_w1,*y_b1,*y_w2,*y_b2,*y_g,*y_be;
  const float *head_w,*head_b;
  float *out;
};

__device__ __forceinline__ float gelu_f(float x){
  // JAX default: approximate (tanh) GELU
  float x3 = x*x*x;
  return 0.5f*x*(1.0f + tanhf(0.7978845608028654f*(x + 0.044715f*x3)));
}

__device__ __forceinline__ float wsum(float v){
  #pragma unroll
  for (int off = 32; off > 0; off >>= 1) v += __shfl_xor(v, off, 64);
  return v;
}

template<int N4>
__device__ __forceinline__ float dot4(const float4* __restrict__ w, const float4* t){
  float a0=0.f,a1=0.f,a2=0.f,a3=0.f;
  #pragma unroll
  for (int i=0;i<N4;++i){
    float4 wa = w[i], ta = t[i];
    a0 += wa.x*ta.x; a1 += wa.y*ta.y; a2 += wa.z*ta.z; a3 += wa.w*ta.w;
  }
  return (a0+a1)+(a2+a3);
}

// ---------------- Kernel A: per-sample tokenizer + 2x self-attn + cross + pool -> xp ----------------
__global__ __launch_bounds__(256) void trm_a(Params p, float* __restrict__ xp_ws, int B){
  __shared__ __align__(16) float xrow[424];
  __shared__ __align__(16) float tok[NTOK*64];    // 3712
  __shared__ __align__(16) float scr[NTOK*192];   // qkv / ff hidden
  __shared__ __align__(16) float attb[NTOK*64];   // attention output
  __shared__ __align__(16) float ctxv[64];        // ctx vector (later reused as pooled)
  __shared__ __align__(16) float cavec[64];       // cross-attn constant add
  __shared__ __align__(16) float xp[128];         // padded (LN96 speculative reads)
  __shared__ __align__(16) float tbuf[152];
  __shared__ float s_mean, s_rs;

  const int b   = blockIdx.x;
  const int tid = threadIdx.x;
  const int lane = tid & 63;
  const int wave = tid >> 6;
  const float* xb = p.x + (long)b*420;

  for (int i = tid; i < 420; i += 256) xrow[i] = xb[i];
  __syncthreads();

  // tokenizer linear (pre-LN)
  for (int idx = tid; idx < NTOK*64; idx += 256){
    int t = idx >> 6, j = idx & 63;
    float acc;
    if (t < 22){
      const float* w = p.mg_w + j*6; const float* s = xrow + t*6;
      acc = p.mg_b[j];
      #pragma unroll
      for (int f = 0; f < 6; ++f) acc += w[f]*s[f];
    } else if (t < 35){
      const float* w = p.dm_w + j*5; const float* s = xrow + 132 + (t-22)*5;
      acc = p.dm_b[j];
      #pragma unroll
      for (int f = 0; f < 5; ++f) acc += w[f]*s[f];
    } else {
      acc = p.al_b[j] + p.al_w[j]*xrow[197 + (t-35)];
    }
    tok[idx] = acc;
  }
  if (tid < 64){ // ctx pre-LN (m2v features 220..419)
    ctxv[tid] = p.mv_b[tid] + dot4<50>((const float4*)(p.mv_w + tid*200), (const float4*)(xrow + 220));
  }
  __syncthreads();

  // per-token LN + gelu (one wave per token)
  for (int t = wave; t < NTOK; t += 4){
    const float *g, *be;
    if (t < 22){ g = p.mg_g; be = p.mg_be; }
    else if (t < 35){ g = p.dm_g; be = p.dm_be; }
    else { g = p.al_g; be = p.al_be; }
    float v = tok[t*64 + lane];
    float m = wsum(v)*(1.f/64.f);
    float d = v - m;
    float var = wsum(d*d)*(1.f/64.f);
    tok[t*64+lane] = gelu_f(d*rsqrtf(var+EPS)*g[lane] + be[lane]);
  }
  __syncthreads();
  if (wave == 0){ // ctx LN + gelu
    float v = ctxv[lane];
    float m = wsum(v)*(1.f/64.f);
    float d = v - m;
    float var = wsum(d*d)*(1.f/64.f);
    ctxv[lane] = gelu_f(d*rsqrtf(var+EPS)*p.mv_g[lane] + p.mv_be[lane]);
  }
  __syncthreads();
  // degenerate cross-attn: softmax over single key == 1 -> out = out_proj(v(ctx)), same for all q
  if (tid < 64) tbuf[tid] = p.ca_in_b[128+tid] + dot4<16>((const float4*)(p.ca_in_w + (128+tid)*64), (const float4*)ctxv);
  __syncthreads();
  if (tid < 64) cavec[tid] = p.ca_out_b[tid] + dot4<16>((const float4*)(p.ca_out_w + tid*64), (const float4*)tbuf);
  __syncthreads();

  for (int pass = 0; pass < 2; ++pass){
    // qkv projection: thread j<192 caches weight row (64 floats) in regs, loops tokens
    if (tid < 192){
      float4 wr[16];
      const float4* w4 = (const float4*)(p.sa_in_w + tid*64);
      #pragma unroll
      for (int i=0;i<16;++i) wr[i] = w4[i];
      float bias = p.sa_in_b[tid];
      for (int t = 0; t < NTOK; ++t){
        const float4* tk = (const float4*)(tok + t*64);
        float a0=0.f,a1=0.f,a2=0.f,a3=0.f;
        #pragma unroll
        for (int i=0;i<16;++i){
          float4 ta = tk[i];
          a0 += wr[i].x*ta.x; a1 += wr[i].y*ta.y; a2 += wr[i].z*ta.z; a3 += wr[i].w*ta.w;
        }
        scr[t*192 + tid] = bias + (a0+a1)+(a2+a3);
      }
    }
    __syncthreads();
    // attention: one thread per (head, query)
    if (tid < 4*NTOK){
      int h = tid / NTOK, qi = tid % NTOK;
      float4 q[4];
      const float4* qp = (const float4*)(scr + qi*192 + h*16);
      #pragma unroll
      for (int i=0;i<4;++i) q[i]=qp[i];
      float mx = -1e30f;
      for (int k = 0; k < NTOK; ++k){
        const float4* kp = (const float4*)(scr + k*192 + 64 + h*16);
        float s = 0.f;
        #pragma unroll
        for (int i=0;i<4;++i){ float4 ka=kp[i]; s += q[i].x*ka.x+q[i].y*ka.y+q[i].z*ka.z+q[i].w*ka.w; }
        mx = fmaxf(mx, s*0.25f);
      }
      float acc[16];
      #pragma unroll
      for (int i=0;i<16;++i) acc[i]=0.f;
      float den = 0.f;
      for (int k = 0; k < NTOK; ++k){
        const float4* kp = (const float4*)(scr + k*192 + 64 + h*16);
        float s = 0.f;
        #pragma unroll
        for (int i=0;i<4;++i){ float4 ka=kp[i]; s += q[i].x*ka.x+q[i].y*ka.y+q[i].z*ka.z+q[i].w*ka.w; }
        float e = expf(s*0.25f - mx);
        den += e;
        const float* vp = scr + k*192 + 128 + h*16;
        #pragma unroll
        for (int i=0;i<16;++i) acc[i] += e*vp[i];
      }
      float inv = 1.f/den;
      float* op = attb + qi*64 + h*16;
      #pragma unroll
      for (int i=0;i<16;++i) op[i] = acc[i]*inv;
    }
    __syncthreads();
    // out-proj + residual (pre-LN), 4 token-groups x 64 output dims
    {
      int j = lane, g = wave;
      int t0 = g*15, t1_ = min(58, t0+15);
      float4 wr[16];
      const float4* w4 = (const float4*)(p.sa_out_w + j*64);
      #pragma unroll
      for (int i=0;i<16;++i) wr[i]=w4[i];
      float bias = p.sa_out_b[j];
      for (int t = t0; t < t1_; ++t){
        const float4* ap = (const float4*)(attb + t*64);
        float a0=0.f,a1=0.f,a2=0.f,a3=0.f;
        #pragma unroll
        for (int i=0;i<16;++i){ float4 aa=ap[i]; a0+=wr[i].x*aa.x; a1+=wr[i].y*aa.y; a2+=wr[i].z*aa.z; a3+=wr[i].w*aa.w; }
        tok[t*64+j] += bias + (a0+a1)+(a2+a3);
      }
    }
    __syncthreads();
    for (int t = wave; t < NTOK; t += 4){ // LN san
      float v = tok[t*64+lane];
      float m = wsum(v)*(1.f/64.f);
      float d = v-m;
      float var = wsum(d*d)*(1.f/64.f);
      tok[t*64+lane] = d*rsqrtf(var+EPS)*p.san_g[lane] + p.san_b[lane];
    }
    __syncthreads();
    // ff1 (64->128, gelu): 128 output dims x 2 token-groups
    {
      int j = tid & 127, g = tid >> 7;
      int t0 = g*29, t1_ = min(58, t0+29);
      float4 wr[16];
      const float4* w4 = (const float4*)(p.ff_w1 + j*64);
      #pragma unroll
      for (int i=0;i<16;++i) wr[i]=w4[i];
      float bias = p.ff_b1[j];
      for (int t = t0; t < t1_; ++t){
        const float4* tk = (const float4*)(tok + t*64);
        float a0=0.f,a1=0.f,a2=0.f,a3=0.f;
        #pragma unroll
        for (int i=0;i<16;++i){ float4 ta=tk[i]; a0+=wr[i].x*ta.x; a1+=wr[i].y*ta.y; a2+=wr[i].z*ta.z; a3+=wr[i].w*ta.w; }
        scr[t*128+j] = gelu_f(bias + (a0+a1)+(a2+a3));
      }
    }
    __syncthreads();
    // ff2 (128->64) + residual: weights streamed (L1-resident, 32KB)
    {
      int j = lane, g = wave;
      int t0 = g*15, t1_ = min(58, t0+15);
      const float4* w4 = (const float4*)(p.ff_w2 + j*128);
      float bias = p.ff_b2[j];
      for (int t = t0; t < t1_; ++t){
        const float4* sp = (const float4*)(scr + t*128);
        float a0=0.f,a1=0.f,a2=0.f,a3=0.f;
        #pragma unroll
        for (int i=0;i<32;++i){ float4 wa=w4[i]; float4 sa=sp[i]; a0+=wa.x*sa.x; a1+=wa.y*sa.y; a2+=wa.z*sa.z; a3+=wa.w*sa.w; }
        tok[t*64+j] += bias + (a0+a1)+(a2+a3);
      }
    }
    __syncthreads();
    for (int t = wave; t < NTOK; t += 4){ // LN saf
      float v = tok[t*64+lane];
      float m = wsum(v)*(1.f/64.f);
      float d = v-m;
      float var = wsum(d*d)*(1.f/64.f);
      tok[t*64+lane] = d*rsqrtf(var+EPS)*p.saf_g[lane] + p.saf_b[lane];
    }
    __syncthreads();
  }

  // cross-attn residual (constant vector) + LN can
  for (int t = wave; t < NTOK; t += 4){
    float v = tok[t*64+lane] + cavec[lane];
    float m = wsum(v)*(1.f/64.f);
    float d = v-m;
    float var = wsum(d*d)*(1.f/64.f);
    tok[t*64+lane] = d*rsqrtf(var+EPS)*p.can_g[lane] + p.can_b[lane];
  }
  __syncthreads();
  // pool (mean over tokens) into ctxv (free now)
  if (tid < 64){
    float s = 0.f;
    for (int t = 0; t < NTOK; ++t) s += tok[t*64 + tid];
    ctxv[tid] = s*(1.f/58.f);
  }
  __syncthreads();
  if (tid < 96) xp[tid] = p.pool_b[tid] + dot4<16>((const float4*)(p.pool_w + tid*64), (const float4*)ctxv);
  __syncthreads();
  if (wave == 0){ // LN over 96 via one wave
    float a = xp[lane];
    float bb = (lane < 32) ? xp[64+lane] : 0.f;
    float m = wsum(a+bb)*(1.f/96.f);
    float da = a-m;
    float db = (lane<32) ? (xp[64+lane]-m) : 0.f;
    float var = wsum(da*da+db*db)*(1.f/96.f);
    if (lane==0){ s_mean=m; s_rs=rsqrtf(var+EPS); }
  }
  __syncthreads();
  if (tid < 96) xp_ws[(long)tid*B + b] = gelu_f((xp[tid]-s_mean)*s_rs*p.pool_g[tid] + p.pool_be[tid]);
}

// ---------------- Kernel B: 20-step recurrence, 32 samples per block ----------------
__global__ __launch_bounds__(256) void trm_b(Params p, const float* __restrict__ xp_ws, int B){
  __shared__ __align__(16) float xpl[96*SB];
  __shared__ __align__(16) float zl [96*SB];
  __shared__ __align__(16) float yl [96*SB];
  __shared__ __align__(16) float t1l[150*SB];
  __shared__ __align__(16) float t2l[96*SB];
  __shared__ float ml[SB], rl[SB];

  const int tid = threadIdx.x;
  const int b0 = blockIdx.x*SB;

  for (int idx = tid; idx < 96*SB; idx += 256){
    int j = idx >> 5, s = idx & 31;
    int b = b0 + s;
    xpl[idx] = (b < B) ? xp_ws[(long)j*B + b] : 0.f;
    zl[idx] = 0.f; yl[idx] = 0.f;
  }
  __syncthreads();

  for (int step = 0; step < 20; ++step){
    // t1 = gelu(z_w1 @ [xp; y; z])
    for (int idx = tid; idx < 150*SB; idx += 256){
      int j = idx >> 5, s = idx & 31;
      const float* w = p.z_w1 + j*288;
      float a0=p.z_b1[j], a1=0.f, a2=0.f, a3=0.f;
      for (int d = 0; d < 96; d += 4){
        a0 += w[d]*xpl[d*32+s];     a1 += w[d+1]*xpl[(d+1)*32+s];
        a2 += w[d+2]*xpl[(d+2)*32+s]; a3 += w[d+3]*xpl[(d+3)*32+s];
      }
      const float* w2 = w + 96;
      for (int d = 0; d < 96; d += 4){
        a0 += w2[d]*yl[d*32+s];     a1 += w2[d+1]*yl[(d+1)*32+s];
        a2 += w2[d+2]*yl[(d+2)*32+s]; a3 += w2[d+3]*yl[(d+3)*32+s];
      }
      const float* w3 = w + 192;
      for (int d = 0; d < 96; d += 4){
        a0 += w3[d]*zl[d*32+s];     a1 += w3[d+1]*zl[(d+1)*32+s];
        a2 += w3[d+2]*zl[(d+2)*32+s]; a3 += w3[d+3]*zl[(d+3)*32+s];
      }
      t1l[idx] = gelu_f((a0+a1)+(a2+a3));
    }
    __syncthreads();
    for (int idx = tid; idx < 96*SB; idx += 256){
      int j = idx >> 5, s = idx & 31;
      const float* w = p.z_w2 + j*150;
      float a0=p.z_b2[j], a1=0.f;
      for (int d = 0; d < 150; d += 2){
        a0 += w[d]*t1l[d*32+s];
        a1 += w[d+1]*t1l[(d+1)*32+s];
      }
      t2l[idx] = a0+a1;
    }
    __syncthreads();
    if (tid < SB){
      float s1 = 0.f;
      for (int d=0; d<96; ++d) s1 += t2l[d*32+tid];
      float m = s1*(1.f/96.f);
      float s2 = 0.f;
      for (int d=0; d<96; ++d){ float v = t2l[d*32+tid]-m; s2 += v*v; }
      ml[tid]=m; rl[tid]=rsqrtf(s2*(1.f/96.f)+EPS);
    }
    __syncthreads();
    for (int idx = tid; idx < 96*SB; idx += 256){
      int j = idx >> 5, s = idx & 31;
      zl[idx] += (t2l[idx]-ml[s])*rl[s]*p.z_g[j] + p.z_be[j];
    }
    __syncthreads();
    // t1 = gelu(y_w1 @ [y; z])  (uses updated z)
    for (int idx = tid; idx < 150*SB; idx += 256){
      int j = idx >> 5, s = idx & 31;
      const float* w = p.y_w1 + j*192;
      float a0=p.y_b1[j], a1=0.f, a2=0.f, a3=0.f;
      for (int d=0; d<96; d+=4){
        a0 += w[d]*yl[d*32+s];     a1 += w[d+1]*yl[(d+1)*32+s];
        a2 += w[d+2]*yl[(d+2)*32+s]; a3 += w[d+3]*yl[(d+3)*32+s];
      }
      const float* w2 = w+96;
      for (int d=0; d<96; d+=4){
        a0 += w2[d]*zl[d*32+s];     a1 += w2[d+1]*zl[(d+1)*32+s];
        a2 += w2[d+2]*zl[(d+2)*32+s]; a3 += w2[d+3]*zl[(d+3)*32+s];
      }
      t1l[idx] = gelu_f((a0+a1)+(a2+a3));
    }
    __syncthreads();
    for (int idx = tid; idx < 96*SB; idx += 256){
      int j = idx >> 5, s = idx & 31;
      const float* w = p.y_w2 + j*150;
      float a0=p.y_b2[j], a1=0.f;
      for (int d=0; d<150; d+=2){
        a0 += w[d]*t1l[d*32+s];
        a1 += w[d+1]*t1l[(d+1)*32+s];
      }
      t2l[idx]=a0+a1;
    }
    __syncthreads();
    if (tid < SB){
      float s1=0.f;
      for (int d=0; d<96; ++d) s1 += t2l[d*32+tid];
      float m = s1*(1.f/96.f);
      float s2=0.f;
      for (int d=0; d<96; ++d){ float v=t2l[d*32+tid]-m; s2 += v*v; }
      ml[tid]=m; rl[tid]=rsqrtf(s2*(1.f/96.f)+EPS);
    }
    __syncthreads();
    for (int idx = tid; idx < 96*SB; idx += 256){
      int j = idx >> 5, s = idx & 31;
      yl[idx] += (t2l[idx]-ml[s])*rl[s]*p.y_g[j] + p.y_be[j];
    }
    __syncthreads();
  }

  if (tid < SB){
    int b = b0 + tid;
    if (b < B){
      float acc = p.head_b[0];
      for (int j=0;j<96;++j) acc += yl[j*32+tid]*p.head_w[j];
      p.out[b] = acc;
    }
  }
}

extern "C" void kernel_launch(void* const* d_in, const int* in_sizes, int n_in,
                              void* d_out, int out_size, void* d_ws, size_t ws_size,
                              hipStream_t stream){
  (void)n_in; (void)out_size; (void)ws_size;
  Params p;
  auto F = [&](int i){ return (const float*)d_in[i]; };
  p.x = F(0);
  p.mg_w=F(1);  p.mg_b=F(2);  p.mg_g=F(3);  p.mg_be=F(4);
  p.dm_w=F(5);  p.dm_b=F(6);  p.dm_g=F(7);  p.dm_be=F(8);
  p.al_w=F(9);  p.al_b=F(10); p.al_g=F(11); p.al_be=F(12);
  p.mv_w=F(13); p.mv_b=F(14); p.mv_g=F(15); p.mv_be=F(16);
  p.sa_in_w=F(17); p.sa_in_b=F(18); p.sa_out_w=F(19); p.sa_out_b=F(20);
  p.san_g=F(21); p.san_b=F(22);
  p.ff_w1=F(23); p.ff_b1=F(24); p.ff_w2=F(25); p.ff_b2=F(26);
  p.saf_g=F(27); p.saf_b=F(28);
  p.ca_in_w=F(29); p.ca_in_b=F(30); p.ca_out_w=F(31); p.ca_out_b=F(32);
  p.can_g=F(33); p.can_b=F(34);
  p.pool_w=F(35); p.pool_b=F(36); p.pool_g=F(37); p.pool_be=F(38);
  p.z_w1=F(39); p.z_b1=F(40); p.z_w2=F(41); p.z_b2=F(42); p.z_g=F(43); p.z_be=F(44);
  p.y_w1=F(45); p.y_b1=F(46); p.y_w2=F(47); p.y_b2=F(48); p.y_g=F(49); p.y_be=F(50);
  p.head_w=F(51); p.head_b=F(52);
  p.out = (float*)d_out;

  int B = in_sizes[0]/420;
  float* xw = (float*)d_ws;   // xp buffer, [96][B] = 6.3 MB

  hipLaunchKernelGGL(trm_a, dim3(B), dim3(256), 0, stream, p, xw, B);
  hipLaunchKernelGGL(trm_b, dim3((B+SB-1)/SB), dim3(256), 0, stream, p, (const float*)xw, B);
}

// Round 3
// 7551.254 us; speedup vs baseline: 2.1754x; 2.1754x over previous
//
#include <hip/hip_runtime.h>
#include <math.h>

#define NTOK 58
#define EPS 1e-5f
#define STOK 200   // scr row stride (floats): (200*q)%32 spreads banks, 16B-aligned
#define SATT 68    // attb row stride

struct Params {
  const float *x;
  const float *mg_w,*mg_b,*mg_g,*mg_be;
  const float *dm_w,*dm_b,*dm_g,*dm_be;
  const float *al_w,*al_b,*al_g,*al_be;
  const float *mv_w,*mv_b,*mv_g,*mv_be;
  const float *sa_in_w,*sa_in_b,*sa_out_w,*sa_out_b,*san_g,*san_b;
  const float *ff_w1,*ff_b1,*ff_w2,*ff_b2,*saf_g,*saf_b;
  const float *ca_in_w,*ca_in_b,*ca_out_w,*ca_out_b,*can_g,*can_b;
  const float *pool_w,*pool_b,*pool_g,*pool_be;
  const float *z_w1,*z_b1,*z_w2,*z_b2,*z_g,*z_be;
  const float *y_w1,*y_b1,*y_w2,*y_b2,*y_g,*y_be;
  const float *head_w,*head_b;
  float *out;
};

__device__ __forceinline__ float gelu_f(float x){
  // tanh-approx GELU (JAX default), tanh via exp
  float a = 0.7978845608028654f*x*(1.0f + 0.044715f*x*x);
  float e = __expf(-2.0f*fabsf(a));
  float th = __fdividef(1.0f - e, 1.0f + e);
  th = (a < 0.0f) ? -th : th;
  return 0.5f*x*(1.0f + th);
}

__device__ __forceinline__ float wsum(float v){
  #pragma unroll
  for (int off = 32; off > 0; off >>= 1) v += __shfl_xor(v, off, 64);
  return v;
}

__device__ __forceinline__ float d4(const float4 a, const float4 b){
  return a.x*b.x + a.y*b.y + a.z*b.z + a.w*b.w;
}

template<int N4>
__device__ __forceinline__ float dotn(const float4* __restrict__ w, const float4* t){
  float a0=0.f,a1=0.f,a2=0.f,a3=0.f;
  #pragma unroll
  for (int i=0;i<N4;++i){
    float4 wa = w[i], ta = t[i];
    a0 += wa.x*ta.x; a1 += wa.y*ta.y; a2 += wa.z*ta.z; a3 += wa.w*ta.w;
  }
  return (a0+a1)+(a2+a3);
}

// ============ Kernel A: tokenizer + 2x self-attn + cross + pool -> xp ============
// 512 threads, ~62KB LDS -> 2 blocks/CU, 4 waves/SIMD.
__global__ __launch_bounds__(512,4) void trm_a(Params p, float* __restrict__ xp_ws, int B){
  __shared__ __align__(16) float tok[NTOK*64];     // 14.8KB
  __shared__ __align__(16) float scr[NTOK*STOK];   // 46.4KB: xrow / qkv / attb / ff-hidden overlays
  __shared__ __align__(16) float ctxv[64];
  __shared__ __align__(16) float cavec[64];
  __shared__ __align__(16) float xpv[96];
  __shared__ __align__(16) float tbuf[64];
  __shared__ float s_mean, s_rs;

  float* xrow = scr;   // [420] overlay, dead after tokenizer
  float* attb = scr;   // [58*SATT] overlay, live only between attention & out-proj

  const int b    = blockIdx.x;
  const int tid  = threadIdx.x;
  const int lane = tid & 63;
  const int wave = tid >> 6;
  const float* xb = p.x + (long)b*420;

  for (int i = tid; i < 420; i += 512) xrow[i] = xb[i];
  __syncthreads();

  // tokenizer linear (pre-LN) + ctx pre-LN
  for (int idx = tid; idx < NTOK*64; idx += 512){
    int t = idx >> 6, j = idx & 63;
    float acc;
    if (t < 22){
      const float* w = p.mg_w + j*6; const float* s = xrow + t*6;
      acc = p.mg_b[j];
      #pragma unroll
      for (int f = 0; f < 6; ++f) acc += w[f]*s[f];
    } else if (t < 35){
      const float* w = p.dm_w + j*5; const float* s = xrow + 132 + (t-22)*5;
      acc = p.dm_b[j];
      #pragma unroll
      for (int f = 0; f < 5; ++f) acc += w[f]*s[f];
    } else {
      acc = p.al_b[j] + p.al_w[j]*xrow[197 + (t-35)];
    }
    tok[idx] = acc;
  }
  if (tid < 64){
    ctxv[tid] = p.mv_b[tid] + dotn<50>((const float4*)(p.mv_w + tid*200), (const float4*)(xrow + 220));
  }
  __syncthreads();   // xrow dead after this

  // per-token LN + gelu (one wave per token)
  for (int t = wave; t < NTOK; t += 8){
    const float *g, *be;
    if (t < 22){ g = p.mg_g; be = p.mg_be; }
    else if (t < 35){ g = p.dm_g; be = p.dm_be; }
    else { g = p.al_g; be = p.al_be; }
    float v = tok[t*64 + lane];
    float m = wsum(v)*(1.f/64.f);
    float d = v - m;
    float var = wsum(d*d)*(1.f/64.f);
    tok[t*64+lane] = gelu_f(d*rsqrtf(var+EPS)*g[lane] + be[lane]);
  }
  __syncthreads();
  if (wave == 0){ // ctx LN + gelu
    float v = ctxv[lane];
    float m = wsum(v)*(1.f/64.f);
    float d = v - m;
    float var = wsum(d*d)*(1.f/64.f);
    ctxv[lane] = gelu_f(d*rsqrtf(var+EPS)*p.mv_g[lane] + p.mv_be[lane]);
  }
  __syncthreads();
  // degenerate cross-attn constant vector: out_proj(v(ctx))
  if (tid < 64) tbuf[tid] = p.ca_in_b[128+tid] + dotn<16>((const float4*)(p.ca_in_w + (128+tid)*64), (const float4*)ctxv);
  __syncthreads();
  if (tid < 64) cavec[tid] = p.ca_out_b[tid] + dotn<16>((const float4*)(p.ca_out_w + tid*64), (const float4*)tbuf);
  __syncthreads();

  for (int pass = 0; pass < 2; ++pass){
    // ---- qkv: 384 thr = (rowgroup48 x quarter4 x tokhalf2); 4 rows x 16-K-quarter per thread
    if (tid < 384){
      const int th = tid >= 192;
      const int u  = th ? tid-192 : tid;
      const int rg = u >> 2, q4 = u & 3;
      const int r0 = rg*4;
      float4 wA[4][4];
      #pragma unroll
      for (int r=0;r<4;++r)
        #pragma unroll
        for (int i=0;i<4;++i)
          wA[r][i] = *(const float4*)(p.sa_in_w + (r0+r)*64 + q4*16 + i*4);
      const float bias = p.sa_in_b[r0+q4];
      for (int tt = th*29; tt < th*29+29; ++tt){
        const float4* tp = (const float4*)(tok + tt*64 + q4*16);
        float4 t4[4];
        #pragma unroll
        for (int i=0;i<4;++i) t4[i] = tp[i];
        float a[4];
        #pragma unroll
        for (int r=0;r<4;++r){
          a[r] = d4(wA[r][0],t4[0]) + d4(wA[r][1],t4[1]) + d4(wA[r][2],t4[2]) + d4(wA[r][3],t4[3]);
        }
        #pragma unroll
        for (int r=0;r<4;++r) a[r] += __shfl_xor(a[r], 1, 64);
        #pragma unroll
        for (int r=0;r<4;++r) a[r] += __shfl_xor(a[r], 2, 64);
        scr[tt*STOK + r0 + q4] = a[q4] + bias;
      }
    }
    __syncthreads();
    // ---- attention: 464 thr = (head4 x query58 x khalf2), online-softmax merge of halves
    {
      const bool act_t = tid < 464;
      int kh=0, h=0, q=0;
      float4 ac[4]; float invden = 0.f;
      if (act_t){
        const int u = tid >> 1; kh = tid & 1;
        h = u / 58; q = u - h*58;
        const int kbase = kh*29;
        float4 qv[4];
        {
          const float4* qp = (const float4*)(scr + q*STOK + h*16);
          #pragma unroll
          for (int i=0;i<4;++i) qv[i] = qp[i];
        }
        float sc[29]; float mx = -1e30f;
        #pragma unroll
        for (int kk=0;kk<29;++kk){
          const float4* kp = (const float4*)(scr + (kbase+kk)*STOK + 64 + h*16);
          float s = d4(qv[0],kp[0]) + d4(qv[1],kp[1]) + d4(qv[2],kp[2]) + d4(qv[3],kp[3]);
          s *= 0.25f;
          sc[kk] = s; mx = fmaxf(mx, s);
        }
        float gm = fmaxf(mx, __shfl_xor(mx, 1, 64));
        float den = 0.f;
        #pragma unroll
        for (int i=0;i<4;++i) ac[i] = make_float4(0.f,0.f,0.f,0.f);
        #pragma unroll
        for (int kk=0;kk<29;++kk){
          float e = __expf(sc[kk] - gm);
          den += e;
          const float4* vp = (const float4*)(scr + (kbase+kk)*STOK + 128 + h*16);
          #pragma unroll
          for (int i=0;i<4;++i){
            float4 v = vp[i];
            ac[i].x += e*v.x; ac[i].y += e*v.y; ac[i].z += e*v.z; ac[i].w += e*v.w;
          }
        }
        den += __shfl_xor(den, 1, 64);
        #pragma unroll
        for (int i=0;i<4;++i){
          ac[i].x += __shfl_xor(ac[i].x, 1, 64);
          ac[i].y += __shfl_xor(ac[i].y, 1, 64);
          ac[i].z += __shfl_xor(ac[i].z, 1, 64);
          ac[i].w += __shfl_xor(ac[i].w, 1, 64);
        }
        invden = __fdividef(1.f, den);
      }
      __syncthreads();   // all scr(k,v) reads done -> safe to overlay attb
      if (act_t && kh == 0){
        float* op = attb + q*SATT + h*16;
        #pragma unroll
        for (int i=0;i<4;++i){
          op[i*4+0] = ac[i].x*invden; op[i*4+1] = ac[i].y*invden;
          op[i*4+2] = ac[i].z*invden; op[i*4+3] = ac[i].w*invden;
        }
      }
      __syncthreads();
    }
    // ---- out-proj + residual: 512 thr = (rg16 x q4 x tokslot8)
    {
      const int t8 = tid >> 6, v6 = tid & 63;
      const int rg = v6 >> 2, q4 = v6 & 3;
      float4 wO[4][4];
      #pragma unroll
      for (int r=0;r<4;++r)
        #pragma unroll
        for (int i=0;i<4;++i)
          wO[r][i] = *(const float4*)(p.sa_out_w + (rg*4+r)*64 + q4*16 + i*4);
      const float bias = p.sa_out_b[rg*4+q4];
      for (int t = t8; t < NTOK; t += 8){
        const float4* ap = (const float4*)(attb + t*SATT + q4*16);
        float4 a4[4];
        #pragma unroll
        for (int i=0;i<4;++i) a4[i] = ap[i];
        float a[4];
        #pragma unroll
        for (int r=0;r<4;++r)
          a[r] = d4(wO[r][0],a4[0]) + d4(wO[r][1],a4[1]) + d4(wO[r][2],a4[2]) + d4(wO[r][3],a4[3]);
        #pragma unroll
        for (int r=0;r<4;++r) a[r] += __shfl_xor(a[r], 1, 64);
        #pragma unroll
        for (int r=0;r<4;++r) a[r] += __shfl_xor(a[r], 2, 64);
        tok[t*64 + rg*4 + q4] += a[q4] + bias;
      }
    }
    __syncthreads();
    for (int t = wave; t < NTOK; t += 8){ // LN san
      float v = tok[t*64+lane];
      float m = wsum(v)*(1.f/64.f);
      float d = v-m;
      float var = wsum(d*d)*(1.f/64.f);
      tok[t*64+lane] = d*rsqrtf(var+EPS)*p.san_g[lane] + p.san_b[lane];
    }
    __syncthreads();
    // ---- ff1 64->128 + gelu: 512 thr = (rg32 x q4 x tq4)
    {
      const int tq = tid >> 7, v7 = tid & 127;
      const int rg = v7 >> 2, q4 = v7 & 3;
      float4 wF[4][4];
      #pragma unroll
      for (int r=0;r<4;++r)
        #pragma unroll
        for (int i=0;i<4;++i)
          wF[r][i] = *(const float4*)(p.ff_w1 + (rg*4+r)*64 + q4*16 + i*4);
      const float bias = p.ff_b1[rg*4+q4];
      for (int t = tq; t < NTOK; t += 4){
        const float4* tp = (const float4*)(tok + t*64 + q4*16);
        float4 t4[4];
        #pragma unroll
        for (int i=0;i<4;++i) t4[i] = tp[i];
        float a[4];
        #pragma unroll
        for (int r=0;r<4;++r)
          a[r] = d4(wF[r][0],t4[0]) + d4(wF[r][1],t4[1]) + d4(wF[r][2],t4[2]) + d4(wF[r][3],t4[3]);
        #pragma unroll
        for (int r=0;r<4;++r) a[r] += __shfl_xor(a[r], 1, 64);
        #pragma unroll
        for (int r=0;r<4;++r) a[r] += __shfl_xor(a[r], 2, 64);
        scr[t*STOK + rg*4 + q4] = gelu_f(a[q4] + bias);
      }
    }
    __syncthreads();
    // ---- ff2 128->64 + residual: 512 thr = (rg16 x q8 x tq4), butterfly over 8 lanes
    {
      const int tq = tid >> 7, v7 = tid & 127;
      const int rg = v7 >> 3, q8 = v7 & 7;
      float4 wF[4][4];
      #pragma unroll
      for (int r=0;r<4;++r)
        #pragma unroll
        for (int i=0;i<4;++i)
          wF[r][i] = *(const float4*)(p.ff_w2 + (rg*4+r)*128 + q8*16 + i*4);
      for (int t = tq; t < NTOK; t += 4){
        const float4* hp = (const float4*)(scr + t*STOK + q8*16);
        float4 h4[4];
        #pragma unroll
        for (int i=0;i<4;++i) h4[i] = hp[i];
        float a[4];
        #pragma unroll
        for (int r=0;r<4;++r)
          a[r] = d4(wF[r][0],h4[0]) + d4(wF[r][1],h4[1]) + d4(wF[r][2],h4[2]) + d4(wF[r][3],h4[3]);
        #pragma unroll
        for (int r=0;r<4;++r) a[r] += __shfl_xor(a[r], 1, 64);
        #pragma unroll
        for (int r=0;r<4;++r) a[r] += __shfl_xor(a[r], 2, 64);
        #pragma unroll
        for (int r=0;r<4;++r) a[r] += __shfl_xor(a[r], 4, 64);
        if (q8 < 4) tok[t*64 + rg*4 + q8] += a[q8] + p.ff_b2[rg*4+q8];
      }
    }
    __syncthreads();
    for (int t = wave; t < NTOK; t += 8){ // LN saf
      float v = tok[t*64+lane];
      float m = wsum(v)*(1.f/64.f);
      float d = v-m;
      float var = wsum(d*d)*(1.f/64.f);
      tok[t*64+lane] = d*rsqrtf(var+EPS)*p.saf_g[lane] + p.saf_b[lane];
    }
    __syncthreads();
  }

  // cross-attn residual (constant vector) + LN can
  for (int t = wave; t < NTOK; t += 8){
    float v = tok[t*64+lane] + cavec[lane];
    float m = wsum(v)*(1.f/64.f);
    float d = v-m;
    float var = wsum(d*d)*(1.f/64.f);
    tok[t*64+lane] = d*rsqrtf(var+EPS)*p.can_g[lane] + p.can_b[lane];
  }
  __syncthreads();
  if (tid < 64){ // pool mean over tokens -> ctxv (free)
    float s = 0.f;
    for (int t = 0; t < NTOK; ++t) s += tok[t*64 + tid];
    ctxv[tid] = s*(1.f/58.f);
  }
  __syncthreads();
  if (tid < 96) xpv[tid] = p.pool_b[tid] + dotn<16>((const float4*)(p.pool_w + tid*64), (const float4*)ctxv);
  __syncthreads();
  if (wave == 0){ // LN over 96
    float a = xpv[lane < 96 ? lane : 0];
    if (lane >= 96) a = 0.f;
    float bb = (lane < 32) ? xpv[64+lane] : 0.f;
    float m = wsum(((lane<64)?a:0.f) + bb)*(1.f/96.f);
    float da = (lane<64) ? (a - m) : 0.f;
    float db = (lane<32) ? (xpv[64+lane]-m) : 0.f;
    float var = wsum(da*da + db*db)*(1.f/96.f);
    if (lane==0){ s_mean=m; s_rs=rsqrtf(var+EPS); }
  }
  __syncthreads();
  if (tid < 96) xp_ws[(long)tid*B + b] = gelu_f((xpv[tid]-s_mean)*s_rs*p.pool_g[tid] + p.pool_be[tid]);
}

// ============ Kernel B: 20-step recurrence, 32 samples/block, LDS-staged weights ============
template<int KC>
__device__ __forceinline__ void accum4(float acc[][4], const float* __restrict__ wbuf,
                                       int jslot, int dd, const float4 av[4]){
  #pragma unroll
  for (int k=0;k<KC;++k){
    float4 wv = *(const float4*)(wbuf + (jslot+32*k)*16 + dd);
    acc[k][0] += wv.x*av[0].x + wv.y*av[1].x + wv.z*av[2].x + wv.w*av[3].x;
    acc[k][1] += wv.x*av[0].y + wv.y*av[1].y + wv.z*av[2].y + wv.w*av[3].y;
    acc[k][2] += wv.x*av[0].z + wv.y*av[1].z + wv.z*av[2].z + wv.w*av[3].z;
    acc[k][3] += wv.x*av[0].w + wv.y*av[1].w + wv.z*av[2].w + wv.w*av[3].w;
  }
}

__global__ __launch_bounds__(256) void trm_b(Params p, const float* __restrict__ xp, int B){
  __shared__ __align__(16) float zl[96*32];     // 12.3KB  [row][32 samples]
  __shared__ __align__(16) float yl[96*32];     // 12.3KB
  __shared__ __align__(16) float t1l[160*32];   // 20.5KB (rows 150..159 = zero pad)
  __shared__ __align__(16) float wbuf[160*16];  // 10.2KB weight chunk [row][16 d]
  __shared__ float ml[32], rl[32];

  const int tid = threadIdx.x;
  const int b0 = blockIdx.x*32;
  const int sg = tid & 7;        // sample group (4 samples: sg*4..sg*4+3)
  const int jslot = tid >> 3;    // 0..31

  for (int i = tid; i < 96*32; i += 256){ zl[i]=0.f; yl[i]=0.f; }
  for (int i = tid; i < 160*32; i += 256) t1l[i]=0.f;
  __syncthreads();

  for (int step = 0; step < 20; ++step){
    // ======= z layer =======
    { // t1 = gelu(z_w1 @ [xp; y; z] + b): K=288, 18 chunks of 16
      float acc[5][4];
      #pragma unroll
      for (int k=0;k<5;++k){ acc[k][0]=acc[k][1]=acc[k][2]=acc[k][3]=0.f; }
      for (int c = 0; c < 18; ++c){
        const int d0 = c*16;
        __syncthreads();
        for (int i = tid; i < 160*16; i += 256){
          int j = i >> 4, d = i & 15;
          wbuf[i] = (j < 150) ? p.z_w1[j*288 + d0 + d] : 0.f;
        }
        __syncthreads();
        #pragma unroll
        for (int dd = 0; dd < 16; dd += 4){
          float4 av[4];
          if (c < 6){
            #pragma unroll
            for (int e=0;e<4;++e) av[e] = *(const float4*)(xp + (size_t)(d0+dd+e)*B + b0 + sg*4);
          } else if (c < 12){
            #pragma unroll
            for (int e=0;e<4;++e) av[e] = *(const float4*)(yl + (d0-96+dd+e)*32 + sg*4);
          } else {
            #pragma unroll
            for (int e=0;e<4;++e) av[e] = *(const float4*)(zl + (d0-192+dd+e)*32 + sg*4);
          }
          accum4<5>(acc, wbuf, jslot, dd, av);
        }
      }
      __syncthreads();
      #pragma unroll
      for (int k=0;k<5;++k){
        int j = jslot + 32*k;
        if (j < 150){
          float bj = p.z_b1[j];
          float4 o = make_float4(gelu_f(acc[k][0]+bj), gelu_f(acc[k][1]+bj),
                                 gelu_f(acc[k][2]+bj), gelu_f(acc[k][3]+bj));
          *(float4*)(t1l + j*32 + sg*4) = o;
        }
      }
      __syncthreads();
    }
    { // t2 = z_w2 @ t1 + b: K=150 (padded 160), then write into t1l[0..96)
      float acc[3][4];
      #pragma unroll
      for (int k=0;k<3;++k){ acc[k][0]=acc[k][1]=acc[k][2]=acc[k][3]=0.f; }
      for (int c = 0; c < 10; ++c){
        const int d0 = c*16;
        __syncthreads();
        for (int i = tid; i < 160*16; i += 256){
          int j = i >> 4, d = i & 15;
          wbuf[i] = (j < 96 && (d0+d) < 150) ? p.z_w2[j*150 + d0 + d] : 0.f;
        }
        __syncthreads();
        #pragma unroll
        for (int dd = 0; dd < 16; dd += 4){
          float4 av[4];
          #pragma unroll
          for (int e=0;e<4;++e) av[e] = *(const float4*)(t1l + (d0+dd+e)*32 + sg*4);
          accum4<3>(acc, wbuf, jslot, dd, av);
        }
      }
      __syncthreads();  // all t1 reads done
      #pragma unroll
      for (int k=0;k<3;++k){
        int j = jslot + 32*k;
        float bj = p.z_b2[j];
        *(float4*)(t1l + j*32 + sg*4) = make_float4(acc[k][0]+bj, acc[k][1]+bj, acc[k][2]+bj, acc[k][3]+bj);
      }
      __syncthreads();
    }
    if (tid < 32){ // LN stats per sample
      float s1 = 0.f;
      for (int j=0;j<96;++j) s1 += t1l[j*32+tid];
      float m = s1*(1.f/96.f);
      float s2 = 0.f;
      for (int j=0;j<96;++j){ float v = t1l[j*32+tid]-m; s2 += v*v; }
      ml[tid]=m; rl[tid]=rsqrtf(s2*(1.f/96.f)+EPS);
    }
    __syncthreads();
    for (int idx = tid; idx < 96*32; idx += 256){
      int j = idx >> 5, s = idx & 31;
      zl[idx] += (t1l[idx]-ml[s])*rl[s]*p.z_g[j] + p.z_be[j];
    }
    __syncthreads();
    // ======= y layer =======
    { // t1 = gelu(y_w1 @ [y; z] + b): K=192, 12 chunks
      float acc[5][4];
      #pragma unroll
      for (int k=0;k<5;++k){ acc[k][0]=acc[k][1]=acc[k][2]=acc[k][3]=0.f; }
      for (int c = 0; c < 12; ++c){
        const int d0 = c*16;
        __syncthreads();
        for (int i = tid; i < 160*16; i += 256){
          int j = i >> 4, d = i & 15;
          wbuf[i] = (j < 150) ? p.y_w1[j*192 + d0 + d] : 0.f;
        }
        __syncthreads();
        #pragma unroll
        for (int dd = 0; dd < 16; dd += 4){
          float4 av[4];
          if (c < 6){
            #pragma unroll
            for (int e=0;e<4;++e) av[e] = *(const float4*)(yl + (d0+dd+e)*32 + sg*4);
          } else {
            #pragma unroll
            for (int e=0;e<4;++e) av[e] = *(const float4*)(zl + (d0-96+dd+e)*32 + sg*4);
          }
          accum4<5>(acc, wbuf, jslot, dd, av);
        }
      }
      __syncthreads();
      #pragma unroll
      for (int k=0;k<5;++k){
        int j = jslot + 32*k;
        if (j < 150){
          float bj = p.y_b1[j];
          float4 o = make_float4(gelu_f(acc[k][0]+bj), gelu_f(acc[k][1]+bj),
                                 gelu_f(acc[k][2]+bj), gelu_f(acc[k][3]+bj));
          *(float4*)(t1l + j*32 + sg*4) = o;
        }
      }
      __syncthreads();
    }
    { // t2 = y_w2 @ t1 + b
      float acc[3][4];
      #pragma unroll
      for (int k=0;k<3;++k){ acc[k][0]=acc[k][1]=acc[k][2]=acc[k][3]=0.f; }
      for (int c = 0; c < 10; ++c){
        const int d0 = c*16;
        __syncthreads();
        for (int i = tid; i < 160*16; i += 256){
          int j = i >> 4, d = i & 15;
          wbuf[i] = (j < 96 && (d0+d) < 150) ? p.y_w2[j*150 + d0 + d] : 0.f;
        }
        __syncthreads();
        #pragma unroll
        for (int dd = 0; dd < 16; dd += 4){
          float4 av[4];
          #pragma unroll
          for (int e=0;e<4;++e) av[e] = *(const float4*)(t1l + (d0+dd+e)*32 + sg*4);
          accum4<3>(acc, wbuf, jslot, dd, av);
        }
      }
      __syncthreads();
      #pragma unroll
      for (int k=0;k<3;++k){
        int j = jslot + 32*k;
        float bj = p.y_b2[j];
        *(float4*)(t1l + j*32 + sg*4) = make_float4(acc[k][0]+bj, acc[k][1]+bj, acc[k][2]+bj, acc[k][3]+bj);
      }
      __syncthreads();
    }
    if (tid < 32){
      float s1 = 0.f;
      for (int j=0;j<96;++j) s1 += t1l[j*32+tid];
      float m = s1*(1.f/96.f);
      float s2 = 0.f;
      for (int j=0;j<96;++j){ float v = t1l[j*32+tid]-m; s2 += v*v; }
      ml[tid]=m; rl[tid]=rsqrtf(s2*(1.f/96.f)+EPS);
    }
    __syncthreads();
    for (int idx = tid; idx < 96*32; idx += 256){
      int j = idx >> 5, s = idx & 31;
      yl[idx] += (t1l[idx]-ml[s])*rl[s]*p.y_g[j] + p.y_be[j];
    }
    __syncthreads();
  }

  if (tid < 32){
    float acc = p.head_b[0];
    for (int j=0;j<96;++j) acc += yl[j*32+tid]*p.head_w[j];
    p.out[b0+tid] = acc;
  }
}

extern "C" void kernel_launch(void* const* d_in, const int* in_sizes, int n_in,
                              void* d_out, int out_size, void* d_ws, size_t ws_size,
                              hipStream_t stream){
  (void)n_in; (void)out_size; (void)ws_size;
  Params p;
  auto F = [&](int i){ return (const float*)d_in[i]; };
  p.x = F(0);
  p.mg_w=F(1);  p.mg_b=F(2);  p.mg_g=F(3);  p.mg_be=F(4);
  p.dm_w=F(5);  p.dm_b=F(6);  p.dm_g=F(7);  p.dm_be=F(8);
  p.al_w=F(9);  p.al_b=F(10); p.al_g=F(11); p.al_be=F(12);
  p.mv_w=F(13); p.mv_b=F(14); p.mv_g=F(15); p.mv_be=F(16);
  p.sa_in_w=F(17); p.sa_in_b=F(18); p.sa_out_w=F(19); p.sa_out_b=F(20);
  p.san_g=F(21); p.san_b=F(22);
  p.ff_w1=F(23); p.ff_b1=F(24); p.ff_w2=F(25); p.ff_b2=F(26);
  p.saf_g=F(27); p.saf_b=F(28);
  p.ca_in_w=F(29); p.ca_in_b=F(30); p.ca_out_w=F(31); p.ca_out_b=F(32);
  p.can_g=F(33); p.can_b=F(34);
  p.pool_w=F(35); p.pool_b=F(36); p.pool_g=F(37); p.pool_be=F(38);
  p.z_w1=F(39); p.z_b1=F(40); p.z_w2=F(41); p.z_b2=F(42); p.z_g=F(43); p.z_be=F(44);
  p.y_w1=F(45); p.y_b1=F(46); p.y_w2=F(47); p.y_b2=F(48); p.y_g=F(49); p.y_be=F(50);
  p.head_w=F(51); p.head_b=F(52);
  p.out = (float*)d_out;

  int B = in_sizes[0]/420;
  float* xw = (float*)d_ws;   // xp buffer [96][B] = 6.3MB

  hipLaunchKernelGGL(trm_a, dim3(B), dim3(512), 0, stream, p, xw, B);
  hipLaunchKernelGGL(trm_b, dim3(B/32), dim3(256), 0, stream, p, (const float*)xw, B);
}